// Round 5
// baseline (719.039 us; speedup 1.0000x reference)
//
#include <hip/hip_runtime.h>
#include <hip/hip_bf16.h>

// BahdanauAttention: B=32, S=2048, H=512, D2=1024
// R5: k_score3 = A(keys fp32) staged via VALU-cvt to swizzled LDS (same image as
// R2-validated DMA layout); B(Uab bf16, L2-resident) frags loaded straight from
// global with register double-buffer. Halves LDS traffic, deletes keys-cvt kernel.

typedef __attribute__((ext_vector_type(8))) short bf16x8;
typedef __attribute__((ext_vector_type(4))) float f32x4;

__device__ __forceinline__ unsigned pk_bf16(float x, float y) {
  union { __hip_bfloat162 h; unsigned u; } c;
  c.h = __float22bfloat162_rn(make_float2(x, y));
  return c.u;
}

__device__ __forceinline__ float fast_tanh(float x) {
  float e = __expf(2.0f * x);
  return 1.0f - 2.0f / (e + 1.0f);
}

// ---- fused: blocks [0,1024): qW + zero scores; [1024,2048): Ua fp32->bf16 ----
__global__ __launch_bounds__(256) void k_fused(const float* __restrict__ query,
                                               const float* __restrict__ Wa_w,
                                               const float* __restrict__ Wa_b,
                                               const float* __restrict__ Ua_b,
                                               const float4* __restrict__ ua,
                                               float* __restrict__ qW,
                                               uint2* __restrict__ ua16,
                                               float* __restrict__ scores) {
  const int t = threadIdx.x;
  if (blockIdx.x >= 1024) {   // ---- Ua cvt: 262144 float4 ----
    size_t i = (size_t)(blockIdx.x - 1024) * 256 + t;
    float4 v = ua[i];
    uint2 o;
    o.x = pk_bf16(v.x, v.y);
    o.y = pk_bf16(v.z, v.w);
    ua16[i] = o;
    return;
  }
  // ---- qW[b][j] = q_cat[b]·Wa_w[j] + Wa_b[j] + Ua_b[j]; + zero scores ----
  if (t < 64) scores[blockIdx.x * 64 + t] = 0.f;
  const int jc = blockIdx.x >> 5, b = blockIdx.x & 31;
  __shared__ float4 qloc[256];
  {
    // q_cat = concat(query[b,1,:], query[b,3,:]); query is (B,4,512)
    const float* base = (t < 128) ? (query + b * 2048 + 512) : (query + b * 2048 + 1536 - 512);
    qloc[t] = *(const float4*)(base + t * 4);
  }
  __syncthreads();
  const int jl = t >> 3, ks = t & 7;
  const int j = jc * 32 + jl;
  const float* wrow = Wa_w + j * 1024;
  float s = 0.f;
  #pragma unroll
  for (int i = 0; i < 32; ++i) {
    float4 wv = *(const float4*)(wrow + i * 32 + ks * 4);
    float4 q4 = qloc[i * 8 + ks];
    s += wv.x * q4.x + wv.y * q4.y + wv.z * q4.z + wv.w * q4.w;
  }
  s += __shfl_xor(s, 1);
  s += __shfl_xor(s, 2);
  s += __shfl_xor(s, 4);
  if (ks == 0) qW[b * 1024 + j] = s + Wa_b[j] + Ua_b[j];
}

// ---- score: tanh(keys@Uab^T + qW)·Va -> scores ----
// 128x128 tile, BK=64. A: fp32 keys -> cvt -> swizzled LDS (16 KB). B: direct
// global frag loads (Uab L2-resident via XCD pin), register double-buffered.
// LDS image identical to R2-proven layout: LDS[row][ls] = G[row][ls ^ (row&7)].
__global__ __launch_bounds__(256) void k_score3(const float* __restrict__ keys,
                                                const unsigned short* __restrict__ Uab,
                                                const float* __restrict__ qW,
                                                const float* __restrict__ Va,
                                                float* __restrict__ scores) {
  __shared__ __align__(16) unsigned short As[128 * 64];  // 16 KB
  const int h = blockIdx.x;
  const int x = h & 7, g = h >> 3;
  const int jblk = g & 7;                    // 0..7
  const int rblk = x + ((g >> 3) << 3);      // 0..511, rblk%8 == h&7 (XCD pin)
  const int t = threadIdx.x;
  const int lane = t & 63, w = t >> 6;
  const int wm = w >> 1, wn = w & 1;
  const int l15 = lane & 15, quad = lane >> 4;
  const int row0 = rblk * 128, j0 = jblk * 128;
  const int rb = l15 & 7;
  const int aoff = (wm * 64 + l15) * 64;

  f32x4 acc[4][4];
  #pragma unroll
  for (int i = 0; i < 4; i++)
    #pragma unroll
    for (int j = 0; j < 4; j++) acc[i][j] = (f32x4){0.f, 0.f, 0.f, 0.f};

  // A staging: thread t -> rows srow+{0,32,64,96}, 8-k slot sslot
  const int srow = t >> 3, sslot = t & 7;
  const float* gA = keys + (size_t)(row0 + srow) * 1024 + sslot * 8;
  unsigned short* lA = As + srow * 64 + ((sslot ^ (srow & 7)) * 8);  // (srow+32p)&7 == srow&7

  // B frags: row_j = j0 + wn*64 + j*16 + l15, k = k0 + ks*32 + quad*8
  const unsigned short* gB = Uab + (size_t)(j0 + wn * 64 + l15) * 1024 + quad * 8;

  auto stage = [&](int k0) {
    #pragma unroll
    for (int p = 0; p < 4; ++p) {
      const float* gp = gA + (size_t)p * 32 * 1024 + k0;
      float4 va = *(const float4*)gp;
      float4 vb = *(const float4*)(gp + 4);
      uint4 o;
      o.x = pk_bf16(va.x, va.y);
      o.y = pk_bf16(va.z, va.w);
      o.z = pk_bf16(vb.x, vb.y);
      o.w = pk_bf16(vb.z, vb.w);
      *(uint4*)(lA + p * 32 * 64) = o;
    }
  };
  auto load_bf = [&](bf16x8 (&bf)[2][4], int k0) {
    #pragma unroll
    for (int ks = 0; ks < 2; ++ks)
      #pragma unroll
      for (int j = 0; j < 4; ++j)
        bf[ks][j] = *(const bf16x8*)(gB + (size_t)j * 16 * 1024 + k0 + ks * 32);
  };
  auto domfma = [&](bf16x8 (&bf)[2][4]) {
    #pragma unroll
    for (int ks = 0; ks < 2; ++ks) {
      const int xf = ((ks * 4 + quad) ^ rb) * 8;
      #pragma unroll
      for (int i = 0; i < 4; ++i) {
        bf16x8 af = *(const bf16x8*)(As + aoff + i * 1024 + xf);
        acc[i][0] = __builtin_amdgcn_mfma_f32_16x16x32_bf16(af, bf[ks][0], acc[i][0], 0, 0, 0);
        acc[i][1] = __builtin_amdgcn_mfma_f32_16x16x32_bf16(af, bf[ks][1], acc[i][1], 0, 0, 0);
        acc[i][2] = __builtin_amdgcn_mfma_f32_16x16x32_bf16(af, bf[ks][2], acc[i][2], 0, 0, 0);
        acc[i][3] = __builtin_amdgcn_mfma_f32_16x16x32_bf16(af, bf[ks][3], acc[i][3], 0, 0, 0);
      }
    }
  };

  bf16x8 bfA[2][4], bfB[2][4];
  load_bf(bfA, 0);
  for (int k0 = 0; k0 < 1024; k0 += 128) {
    if (k0) __syncthreads();       // prior frag reads done before As overwrite
    stage(k0);
    load_bf(bfB, k0 + 64);         // in flight across the barrier region
    __syncthreads();
    domfma(bfA);
    __syncthreads();
    stage(k0 + 64);
    if (k0 + 128 < 1024) load_bf(bfA, k0 + 128);
    __syncthreads();
    domfma(bfB);
  }

  // epilogue: scores[r] += sum_j Va[j]*tanh(acc + qW[b][j]); Va_b dropped (shift-inv)
  const int b = row0 >> 11;
  float va[4], qb[4];
  #pragma unroll
  for (int j = 0; j < 4; j++) {
    int jg = j0 + wn * 64 + j * 16 + l15;
    va[j] = Va[jg];
    qb[j] = qW[b * 1024 + jg];
  }
  #pragma unroll
  for (int i = 0; i < 4; i++) {
    #pragma unroll
    for (int r = 0; r < 4; r++) {
      float s = 0.f;
      #pragma unroll
      for (int j = 0; j < 4; j++)
        s += va[j] * fast_tanh(acc[i][j][r] + qb[j]);
      s += __shfl_xor(s, 1);
      s += __shfl_xor(s, 2);
      s += __shfl_xor(s, 4);
      s += __shfl_xor(s, 8);
      if (l15 == 0) {
        int rg = row0 + wm * 64 + i * 16 + quad * 4 + r;   // C/D: row = quad*4+reg
        atomicAdd(&scores[rg], s);
      }
    }
  }
}

// ---- softmax over S=2048 per batch -> weights; also zero ctx[b] ----
__global__ __launch_bounds__(256) void k_softmax(const float* __restrict__ scores,
                                                 float* __restrict__ wout,
                                                 float* __restrict__ ctx) {
  const int b = blockIdx.x, t = threadIdx.x;
  const int lane = t & 63, w = t >> 6;
  *(float4*)(ctx + b * 1024 + t * 4) = (float4){0.f, 0.f, 0.f, 0.f};
  __shared__ float red[4];
  float v[8];
  float mx = -1e30f;
  #pragma unroll
  for (int i = 0; i < 8; i++) {
    v[i] = scores[b * 2048 + i * 256 + t];
    mx = fmaxf(mx, v[i]);
  }
  #pragma unroll
  for (int off = 1; off < 64; off <<= 1) mx = fmaxf(mx, __shfl_xor(mx, off));
  if (lane == 0) red[w] = mx;
  __syncthreads();
  mx = fmaxf(fmaxf(red[0], red[1]), fmaxf(red[2], red[3]));
  float sum = 0.f;
  #pragma unroll
  for (int i = 0; i < 8; i++) {
    v[i] = __expf(v[i] - mx);
    sum += v[i];
  }
  #pragma unroll
  for (int off = 1; off < 64; off <<= 1) sum += __shfl_xor(sum, off);
  __syncthreads();
  if (lane == 0) red[w] = sum;
  __syncthreads();
  sum = red[0] + red[1] + red[2] + red[3];
  float inv = 1.0f / sum;
  #pragma unroll
  for (int i = 0; i < 8; i++) wout[b * 2048 + i * 256 + t] = v[i] * inv;
}

// ---- context[b][d] = sum_s w[b][s]*keys[b][s][d]  (fp32 keys, HBM-bound) ----
__global__ __launch_bounds__(256) void k_context(const float* __restrict__ keys,
                                                 const float* __restrict__ wts,
                                                 float* __restrict__ ctx) {
  const int sc = blockIdx.x;   // 0..31 (64 s each)
  const int b  = blockIdx.y;   // 0..31
  const int t  = threadIdx.x;
  __shared__ float wl[64];
  if (t < 64) wl[t] = wts[b * 2048 + sc * 64 + t];
  __syncthreads();
  const float4* kp = (const float4*)(keys + ((size_t)(b * 2048 + sc * 64) << 10)) + t;
  float4 a = {0.f, 0.f, 0.f, 0.f};
  #pragma unroll 8
  for (int s = 0; s < 64; ++s) {
    float4 kv = kp[s * 256];
    float wv = wl[s];
    a.x += wv * kv.x; a.y += wv * kv.y; a.z += wv * kv.z; a.w += wv * kv.w;
  }
  float* o = ctx + b * 1024 + t * 4;
  atomicAdd(o + 0, a.x);
  atomicAdd(o + 1, a.y);
  atomicAdd(o + 2, a.z);
  atomicAdd(o + 3, a.w);
}

extern "C" void kernel_launch(void* const* d_in, const int* in_sizes, int n_in,
                              void* d_out, int out_size, void* d_ws, size_t ws_size,
                              hipStream_t stream) {
  const float* query = (const float*)d_in[0];
  const float* keys  = (const float*)d_in[1];
  const float* Wa_w  = (const float*)d_in[2];
  const float* Wa_b  = (const float*)d_in[3];
  const float* Ua_w  = (const float*)d_in[4];
  const float* Ua_b  = (const float*)d_in[5];
  const float* Va_w  = (const float*)d_in[6];
  // d_in[7] = Va_b: unused (softmax shift-invariance)

  // ws layout (2.4 MB): scores[65536] f32 | qW[32768] f32 | Uab 1M bf16
  float* scores = (float*)d_ws;
  float* qW     = scores + 65536;
  unsigned short* Uab = (unsigned short*)(qW + 32768);

  float* ctx = (float*)d_out;        // context: 32*1024
  float* wts = ctx + 32768;          // weights: 32*2048

  k_fused<<<2048, 256, 0, stream>>>(query, Wa_w, Wa_b, Ua_b, (const float4*)Ua_w,
                                    qW, (uint2*)Uab, scores);
  k_score3<<<4096, 256, 0, stream>>>(keys, Uab, qW, Va_w, scores);
  k_softmax<<<32, 256, 0, stream>>>(scores, wts, ctx);
  k_context<<<dim3(32, 32), 256, 0, stream>>>(keys, wts, ctx);
}

// Round 6
// 563.284 us; speedup vs baseline: 1.2765x; 1.2765x over previous
//
#include <hip/hip_runtime.h>
#include <hip/hip_bf16.h>

// BahdanauAttention: B=32, S=2048, H=512, D2=1024
// R6: k_score4 = R5's A-path (fp32 keys -> VALU cvt -> swizzled ds_write_b128)
// + R4's B-path (global_load_lds DMA from L2-resident Uab -> Bs, frag reads
// from LDS). No keys16 workspace (ws = 2.4 MB), no separate keys-cvt kernel.

typedef __attribute__((ext_vector_type(8))) short bf16x8;
typedef __attribute__((ext_vector_type(4))) float f32x4;

__device__ __forceinline__ unsigned pk_bf16(float x, float y) {
  union { __hip_bfloat162 h; unsigned u; } c;
  c.h = __float22bfloat162_rn(make_float2(x, y));
  return c.u;
}

__device__ __forceinline__ float fast_tanh(float x) {
  float e = __expf(2.0f * x);
  return 1.0f - 2.0f / (e + 1.0f);
}

// async global->LDS, 16B per lane; LDS dest = wave-uniform base + lane*16
typedef const __attribute__((address_space(1))) void* gas_t;
typedef __attribute__((address_space(3))) void* las_t;
__device__ __forceinline__ void ld_lds16(const void* g, void* l) {
  __builtin_amdgcn_global_load_lds((gas_t)g, (las_t)l, 16, 0, 0);
}

// ---- fused: blocks [0,1024): qW + zero scores; [1024,2048): Ua fp32->bf16 ----
__global__ __launch_bounds__(256) void k_fused(const float* __restrict__ query,
                                               const float* __restrict__ Wa_w,
                                               const float* __restrict__ Wa_b,
                                               const float* __restrict__ Ua_b,
                                               const float4* __restrict__ ua,
                                               float* __restrict__ qW,
                                               uint2* __restrict__ ua16,
                                               float* __restrict__ scores) {
  const int t = threadIdx.x;
  if (blockIdx.x >= 1024) {   // ---- Ua cvt: 262144 float4 ----
    size_t i = (size_t)(blockIdx.x - 1024) * 256 + t;
    float4 v = ua[i];
    uint2 o;
    o.x = pk_bf16(v.x, v.y);
    o.y = pk_bf16(v.z, v.w);
    ua16[i] = o;
    return;
  }
  // ---- qW[b][j] = q_cat[b]·Wa_w[j] + Wa_b[j] + Ua_b[j]; + zero scores ----
  if (t < 64) scores[blockIdx.x * 64 + t] = 0.f;
  const int jc = blockIdx.x >> 5, b = blockIdx.x & 31;
  __shared__ float4 qloc[256];
  {
    // q_cat = concat(query[b,1,:], query[b,3,:]); query is (B,4,512)
    const float* base = (t < 128) ? (query + b * 2048 + 512) : (query + b * 2048 + 1536 - 512);
    qloc[t] = *(const float4*)(base + t * 4);
  }
  __syncthreads();
  const int jl = t >> 3, ks = t & 7;
  const int j = jc * 32 + jl;
  const float* wrow = Wa_w + j * 1024;
  float s = 0.f;
  #pragma unroll
  for (int i = 0; i < 32; ++i) {
    float4 wv = *(const float4*)(wrow + i * 32 + ks * 4);
    float4 q4 = qloc[i * 8 + ks];
    s += wv.x * q4.x + wv.y * q4.y + wv.z * q4.z + wv.w * q4.w;
  }
  s += __shfl_xor(s, 1);
  s += __shfl_xor(s, 2);
  s += __shfl_xor(s, 4);
  if (ks == 0) qW[b * 1024 + j] = s + Wa_b[j] + Ua_b[j];
}

// ---- score: tanh(keys@Uab^T + qW)·Va -> scores (atomic) ----
// 128x128 tile, BK=64, 2 barriers/iter (R4 structure).
// A: fp32 keys -> cvt_pk -> swizzled ds_write_b128 (R5-proven image:
//    LDS[row][ls] = G[row][ls ^ (row&7)], 16B slots).
// B: global_load_lds DMA from Uab (bf16, L2-resident via XCD pin).
// XCD pin: rblk%8 == blockIdx.x&7 -> 8 jblk siblings of a row-block on one XCD.
__global__ __launch_bounds__(256) void k_score4(const float* __restrict__ keys,
                                                const unsigned short* __restrict__ Uab,
                                                const float* __restrict__ qW,
                                                const float* __restrict__ Va,
                                                float* __restrict__ scores) {
  __shared__ __align__(16) unsigned short As[128 * 64];  // 16 KB
  __shared__ __align__(16) unsigned short Bs[128 * 64];  // 16 KB
  const int h = blockIdx.x;
  const int x = h & 7, g = h >> 3;
  const int jblk = g & 7;                    // 0..7
  const int rblk = x + ((g >> 3) << 3);      // 0..511, rblk%8 == h&7 (XCD pin)
  const int t = threadIdx.x;
  const int lane = t & 63, w = t >> 6;
  const int wm = w >> 1, wn = w & 1;
  const int l15 = lane & 15, quad = lane >> 4;
  const int row0 = rblk * 128, j0 = jblk * 128;
  const int rb = l15 & 7;
  const int aoff = (wm * 64 + l15) * 64;
  const int boff = (wn * 64 + l15) * 64;

  f32x4 acc[4][4];
  #pragma unroll
  for (int i = 0; i < 4; i++)
    #pragma unroll
    for (int j = 0; j < 4; j++) acc[i][j] = (f32x4){0.f, 0.f, 0.f, 0.f};

  // A staging: thread t -> rows (t>>3)+{0,32,64,96}, 8-k slot (t&7)
  const int srow = t >> 3, sslot = t & 7;
  const float* gA = keys + (size_t)(row0 + srow) * 1024 + sslot * 8;
  unsigned short* lA = As + srow * 64 + ((sslot ^ (srow & 7)) * 8);  // (srow+32p)&7==srow&7

  // B DMA: chunk = 1KB = 8 rows x 128B; wave w stages chunks w*4+i
  const int lr = lane >> 3;                  // row-in-chunk 0..7
  const int sg = (lane & 7) ^ lr;            // swizzled 16B slot
  const unsigned short* gB = Uab + (size_t)(j0 + (w * 4) * 8 + lr) * 1024 + sg * 8;

  for (int k0 = 0; k0 < 1024; k0 += 64) {
    if (k0) __syncthreads();   // prior frag reads done before overwrite
    // A global loads first (long-latency fp32), then B DMA, then cvt+write
    float4 ra[4][2];
    #pragma unroll
    for (int p = 0; p < 4; ++p) {
      const float* gp = gA + (size_t)p * 32 * 1024 + k0;
      ra[p][0] = *(const float4*)gp;
      ra[p][1] = *(const float4*)(gp + 4);
    }
    #pragma unroll
    for (int i = 0; i < 4; ++i)
      ld_lds16(gB + (size_t)i * 8 * 1024 + k0, Bs + (w * 4 + i) * 512);
    #pragma unroll
    for (int p = 0; p < 4; ++p) {
      uint4 o;
      o.x = pk_bf16(ra[p][0].x, ra[p][0].y);
      o.y = pk_bf16(ra[p][0].z, ra[p][0].w);
      o.z = pk_bf16(ra[p][1].x, ra[p][1].y);
      o.w = pk_bf16(ra[p][1].z, ra[p][1].w);
      *(uint4*)(lA + p * 32 * 64) = o;
    }
    __syncthreads();           // drains vmcnt(0)+lgkm: both tiles resident
    #pragma unroll
    for (int ks = 0; ks < 2; ++ks) {
      const int xf = ((ks * 4 + quad) ^ rb) * 8;   // swizzled frag slot
      bf16x8 bfr0 = *(const bf16x8*)(Bs + boff + 0 * 1024 + xf);
      bf16x8 bfr1 = *(const bf16x8*)(Bs + boff + 1 * 1024 + xf);
      bf16x8 bfr2 = *(const bf16x8*)(Bs + boff + 2 * 1024 + xf);
      bf16x8 bfr3 = *(const bf16x8*)(Bs + boff + 3 * 1024 + xf);
      #pragma unroll
      for (int i = 0; i < 4; i++) {
        bf16x8 af = *(const bf16x8*)(As + aoff + i * 1024 + xf);
        acc[i][0] = __builtin_amdgcn_mfma_f32_16x16x32_bf16(af, bfr0, acc[i][0], 0, 0, 0);
        acc[i][1] = __builtin_amdgcn_mfma_f32_16x16x32_bf16(af, bfr1, acc[i][1], 0, 0, 0);
        acc[i][2] = __builtin_amdgcn_mfma_f32_16x16x32_bf16(af, bfr2, acc[i][2], 0, 0, 0);
        acc[i][3] = __builtin_amdgcn_mfma_f32_16x16x32_bf16(af, bfr3, acc[i][3], 0, 0, 0);
      }
    }
  }

  // epilogue: scores[r] += sum_j Va[j]*tanh(acc + qW[b][j]); Va_b dropped (shift-inv)
  const int b = row0 >> 11;
  float va[4], qb[4];
  #pragma unroll
  for (int j = 0; j < 4; j++) {
    int jg = j0 + wn * 64 + j * 16 + l15;
    va[j] = Va[jg];
    qb[j] = qW[b * 1024 + jg];
  }
  #pragma unroll
  for (int i = 0; i < 4; i++) {
    #pragma unroll
    for (int r = 0; r < 4; r++) {
      float s = 0.f;
      #pragma unroll
      for (int j = 0; j < 4; j++)
        s += va[j] * fast_tanh(acc[i][j][r] + qb[j]);
      s += __shfl_xor(s, 1);
      s += __shfl_xor(s, 2);
      s += __shfl_xor(s, 4);
      s += __shfl_xor(s, 8);
      if (l15 == 0) {
        int rg = row0 + wm * 64 + i * 16 + quad * 4 + r;   // C/D: row = quad*4+reg
        atomicAdd(&scores[rg], s);
      }
    }
  }
}

// ---- softmax over S=2048 per batch -> weights; also zero ctx[b] ----
__global__ __launch_bounds__(256) void k_softmax(const float* __restrict__ scores,
                                                 float* __restrict__ wout,
                                                 float* __restrict__ ctx) {
  const int b = blockIdx.x, t = threadIdx.x;
  const int lane = t & 63, w = t >> 6;
  *(float4*)(ctx + b * 1024 + t * 4) = (float4){0.f, 0.f, 0.f, 0.f};
  __shared__ float red[4];
  float v[8];
  float mx = -1e30f;
  #pragma unroll
  for (int i = 0; i < 8; i++) {
    v[i] = scores[b * 2048 + i * 256 + t];
    mx = fmaxf(mx, v[i]);
  }
  #pragma unroll
  for (int off = 1; off < 64; off <<= 1) mx = fmaxf(mx, __shfl_xor(mx, off));
  if (lane == 0) red[w] = mx;
  __syncthreads();
  mx = fmaxf(fmaxf(red[0], red[1]), fmaxf(red[2], red[3]));
  float sum = 0.f;
  #pragma unroll
  for (int i = 0; i < 8; i++) {
    v[i] = __expf(v[i] - mx);
    sum += v[i];
  }
  #pragma unroll
  for (int off = 1; off < 64; off <<= 1) sum += __shfl_xor(sum, off);
  __syncthreads();
  if (lane == 0) red[w] = sum;
  __syncthreads();
  sum = red[0] + red[1] + red[2] + red[3];
  float inv = 1.0f / sum;
  #pragma unroll
  for (int i = 0; i < 8; i++) wout[b * 2048 + i * 256 + t] = v[i] * inv;
}

// ---- context[b][d] = sum_s w[b][s]*keys[b][s][d]  (fp32 keys, HBM-bound) ----
__global__ __launch_bounds__(256) void k_context(const float* __restrict__ keys,
                                                 const float* __restrict__ wts,
                                                 float* __restrict__ ctx) {
  const int sc = blockIdx.x;   // 0..31 (64 s each)
  const int b  = blockIdx.y;   // 0..31
  const int t  = threadIdx.x;
  __shared__ float wl[64];
  if (t < 64) wl[t] = wts[b * 2048 + sc * 64 + t];
  __syncthreads();
  const float4* kp = (const float4*)(keys + ((size_t)(b * 2048 + sc * 64) << 10)) + t;
  float4 a = {0.f, 0.f, 0.f, 0.f};
  #pragma unroll 8
  for (int s = 0; s < 64; ++s) {
    float4 kv = kp[s * 256];
    float wv = wl[s];
    a.x += wv * kv.x; a.y += wv * kv.y; a.z += wv * kv.z; a.w += wv * kv.w;
  }
  float* o = ctx + b * 1024 + t * 4;
  atomicAdd(o + 0, a.x);
  atomicAdd(o + 1, a.y);
  atomicAdd(o + 2, a.z);
  atomicAdd(o + 3, a.w);
}

extern "C" void kernel_launch(void* const* d_in, const int* in_sizes, int n_in,
                              void* d_out, int out_size, void* d_ws, size_t ws_size,
                              hipStream_t stream) {
  const float* query = (const float*)d_in[0];
  const float* keys  = (const float*)d_in[1];
  const float* Wa_w  = (const float*)d_in[2];
  const float* Wa_b  = (const float*)d_in[3];
  const float* Ua_w  = (const float*)d_in[4];
  const float* Ua_b  = (const float*)d_in[5];
  const float* Va_w  = (const float*)d_in[6];
  // d_in[7] = Va_b: unused (softmax shift-invariance)

  // ws layout (2.4 MB): scores[65536] f32 | qW[32768] f32 | Uab 1M bf16
  float* scores = (float*)d_ws;
  float* qW     = scores + 65536;
  unsigned short* Uab = (unsigned short*)(qW + 32768);

  float* ctx = (float*)d_out;        // context: 32*1024
  float* wts = ctx + 32768;          // weights: 32*2048

  k_fused<<<2048, 256, 0, stream>>>(query, Wa_w, Wa_b, Ua_b, (const float4*)Ua_w,
                                    qW, (uint2*)Uab, scores);
  k_score4<<<4096, 256, 0, stream>>>(keys, Uab, qW, Va_w, scores);
  k_softmax<<<32, 256, 0, stream>>>(scores, wts, ctx);
  k_context<<<dim3(32, 32), 256, 0, stream>>>(keys, wts, ctx);
}